// Round 12
// baseline (333.937 us; speedup 1.0000x reference)
//
#include <hip/hip_runtime.h>

// MoE forward, MI355X. fp32 router/dispatch (exact top-k), bf16 MFMA grouped
// GEMMs (9 groups = 8 experts + shared), fp32-atomic scatter-combine.
// R11: overhead consolidation. zero + 4x tconv + router fused into ONE
// prep_kernel (independent work, branch by block range; tconv segments run
// concurrently instead of serially; 4 launch gaps removed). Router stats via
// per-block partials (no global atomics/pre-zero); aux fused into dispatch.
// 9 launches -> 4. GEMMs byte-identical to R10 (128x128, 4 waves, single-
// buffer, launch_bounds(256,4) = 4 blocks/CU; 131-133us each, verified x3).

#define NTOK 8192
#define DDIM 1024
#define HDIM 1408
#define CAP  2560
#define NROWS (NTOK + 8*CAP)   // 28672 GEMM rows: [0,8192) shared, then 8*2560 expert slots
#define YN   8388608           // NTOK*DDIM

typedef __bf16 bf16x8 __attribute__((ext_vector_type(8)));
typedef float  f32x4  __attribute__((ext_vector_type(4)));

typedef __attribute__((address_space(1))) void gvoid_t;
typedef __attribute__((address_space(3))) void svoid_t;

static __device__ __forceinline__ void load_lds16(const void* g, void* l) {
  // 16B per lane, LDS dest = wave-uniform base + lane*16 (linear)
  __builtin_amdgcn_global_load_lds((gvoid_t*)g, (svoid_t*)l, 16, 0, 0);
}

// ---------------- fused prep: router+convx | zero y | 4x weight transpose ----------------
// Block ranges: [0,256) router, [256,2304) zero y, [2304,13568) wfc,
// [13568,14976) wsfc, [14976,26240) wproj, [26240,27648) wsproj.
__device__ __forceinline__ void tconv_body(const float* __restrict__ in,
                                           __bf16* __restrict__ out,
                                           int R, int C, int bx, int by,
                                           float* shbuf, int tid) {
  float (*t)[33] = (float(*)[33])shbuf;
  int c0 = bx * 32, r0 = by * 32;
  int tx = tid & 31, ty = tid >> 5;  // (32,8)
#pragma unroll
  for (int k2 = 0; k2 < 4; ++k2)
    t[ty + k2 * 8][tx] = in[(size_t)(r0 + ty + k2 * 8) * C + c0 + tx];
  __syncthreads();
#pragma unroll
  for (int k2 = 0; k2 < 4; ++k2)
    out[(size_t)(c0 + ty + k2 * 8) * R + r0 + tx] = (__bf16)t[tx][ty + k2 * 8];
}

__global__ __launch_bounds__(256) void prep_kernel(
    const float* __restrict__ x, const float* __restrict__ rw,
    __bf16* __restrict__ xbf,
    int2* __restrict__ e01, float2* __restrict__ p01,
    int* __restrict__ tok_row, float* __restrict__ scale_row,
    float* __restrict__ psum_part, int* __restrict__ fcnt_part,
    const float* __restrict__ wfc, const float* __restrict__ wsfc,
    const float* __restrict__ wproj, const float* __restrict__ wsproj,
    __bf16* __restrict__ B1, __bf16* __restrict__ B2,
    float* __restrict__ y) {
  __shared__ float shbuf[8192];   // router: rw cache (32 KB); tconv: 32x33 tile
  __shared__ float ps[8];
  __shared__ int fc[8];
  int b = blockIdx.x, tid = threadIdx.x;

  if (b < 256) {
    // ---- router + fused x->bf16 convert ----
    if (tid < 8) { ps[tid] = 0.f; fc[tid] = 0; }
    float4* rl4 = (float4*)shbuf;
    const float4* rg4 = (const float4*)rw;
#pragma unroll
    for (int j = 0; j < 8; ++j) rl4[tid + 256 * j] = rg4[tid + 256 * j];
    __syncthreads();
    int lane = tid & 63, wid = tid >> 6;
    for (int it = 0; it < 8; ++it) {
      int t = b * 32 + wid * 8 + it;
      const float4* xt = (const float4*)(x + (size_t)t * DDIM);
      float a[8];
#pragma unroll
      for (int e = 0; e < 8; ++e) a[e] = 0.f;
      float4 v[4];
#pragma unroll
      for (int jj = 0; jj < 4; ++jj) {
        v[jj] = xt[lane * 4 + jj];
#pragma unroll
        for (int e = 0; e < 8; ++e) {
          float4 w = rl4[e * 256 + lane * 4 + jj];
          a[e] += v[jj].x * w.x + v[jj].y * w.y + v[jj].z * w.z + v[jj].w * w.w;
        }
      }
      {
        bf16x8 o0, o1;
#pragma unroll
        for (int jj = 0; jj < 2; ++jj) {
          o0[jj * 4 + 0] = (__bf16)v[jj].x; o0[jj * 4 + 1] = (__bf16)v[jj].y;
          o0[jj * 4 + 2] = (__bf16)v[jj].z; o0[jj * 4 + 3] = (__bf16)v[jj].w;
          o1[jj * 4 + 0] = (__bf16)v[jj + 2].x; o1[jj * 4 + 1] = (__bf16)v[jj + 2].y;
          o1[jj * 4 + 2] = (__bf16)v[jj + 2].z; o1[jj * 4 + 3] = (__bf16)v[jj + 2].w;
        }
        __bf16* xo = xbf + (size_t)t * DDIM + lane * 16;
        *(bf16x8*)xo = o0;
        *(bf16x8*)(xo + 8) = o1;
      }
#pragma unroll
      for (int off = 32; off >= 1; off >>= 1)
#pragma unroll
        for (int e = 0; e < 8; ++e) a[e] += __shfl_xor(a[e], off);
      if (lane == 0) {
        int am = 0; float m = a[0];
        for (int e = 1; e < 8; ++e) if (a[e] > m) { m = a[e]; am = e; }
        float s = 0.f, ex[8];
        for (int e = 0; e < 8; ++e) { ex[e] = expf(a[e] - m); s += ex[e]; }
        float inv = 1.f / s;
        int am2 = -1; float m2 = -3.4e38f;
        for (int e = 0; e < 8; ++e) if (e != am && a[e] > m2) { m2 = a[e]; am2 = e; }
        float p0 = ex[am] * inv, p1 = ex[am2] * inv;
        float rn = 1.f / (p0 + p1 + 1e-9f);
        e01[t] = make_int2(am, am2);
        p01[t] = make_float2(p0 * rn, p1 * rn);
        tok_row[t] = t;            // shared-group rows: identity gather, weight 1
        scale_row[t] = 1.f;
        atomicAdd(&fc[am], 1);
        for (int e = 0; e < 8; ++e) atomicAdd(&ps[e], ex[e] * inv);
      }
    }
    __syncthreads();
    if (tid < 8) { psum_part[b * 8 + tid] = ps[tid]; fcnt_part[b * 8 + tid] = fc[tid]; }
    return;
  }
  b -= 256;
  if (b < 2048) {
    // ---- zero y (atomic-combine target) ----
    size_t idx = (size_t)b * 256 + tid;
    float4 z = make_float4(0.f, 0.f, 0.f, 0.f);
    float4* p = (float4*)y;
#pragma unroll
    for (int j = 0; j < 4; ++j) p[idx + (size_t)j * 524288] = z;
    return;
  }
  b -= 2048;
  if (b < 11264) {  // wfc [e][1024][1408] -> B1[e][1408][1024]
    int e = b / 1408, r = b % 1408;
    tconv_body(wfc + (size_t)e * 1024 * 1408, B1 + (size_t)e * HDIM * DDIM,
               1024, 1408, r % 44, r / 44, shbuf, tid);
    return;
  }
  b -= 11264;
  if (b < 1408) {   // wsfc -> B1[8]
    tconv_body(wsfc, B1 + (size_t)8 * HDIM * DDIM, 1024, 1408, b % 44, b / 44, shbuf, tid);
    return;
  }
  b -= 1408;
  if (b < 11264) {  // wproj [e][1408][1024] -> B2[e][1024][1408]
    int e = b / 1408, r = b % 1408;
    tconv_body(wproj + (size_t)e * 1408 * 1024, B2 + (size_t)e * DDIM * HDIM,
               1408, 1024, r % 32, r / 32, shbuf, tid);
    return;
  }
  b -= 11264;
  {                 // wsproj -> B2[8]
    tconv_body(wsproj, B2 + (size_t)8 * DDIM * HDIM, 1408, 1024, b % 32, b / 32, shbuf, tid);
  }
}

// ------- dispatch (+stat reduce +aux): stable rank within expert, capacity drop -------
__global__ __launch_bounds__(256) void dispatch_kernel(
    const int2* __restrict__ e01, const float2* __restrict__ p01,
    int* __restrict__ tok_row, float* __restrict__ scale_row, int* __restrict__ counts,
    const float* __restrict__ psum_part, const int* __restrict__ fcnt_part,
    float* __restrict__ aux_out) {
  __shared__ int lcnt[256][8];
  __shared__ float aps[8];
  __shared__ int afc[8];
  int tid = threadIdx.x;
  // reduce router per-block stats (independent of dispatch logic)
  if (tid < 8) {
    float s = 0.f; int c = 0;
    for (int i = 0; i < 256; ++i) { s += psum_part[i * 8 + tid]; c += fcnt_part[i * 8 + tid]; }
    aps[tid] = s; afc[tid] = c;
  }
  int my[8];
#pragma unroll
  for (int e = 0; e < 8; ++e) my[e] = 0;
  int base = tid * 64;  // 256 threads * 64 entries = 16384 = N*K, contiguous => stable
  for (int j = 0; j < 64; ++j) {
    int ent = base + j; int t = ent >> 1;
    int2 ee = e01[t];
    int ex = (ent & 1) ? ee.y : ee.x;
    my[ex]++;
  }
#pragma unroll
  for (int e = 0; e < 8; ++e) lcnt[tid][e] = my[e];
  __syncthreads();
  if (tid < 8) {
    int run = 0;
    for (int i = 0; i < 256; ++i) { int c = lcnt[i][tid]; lcnt[i][tid] = run; run += c; }
    counts[tid] = run < CAP ? run : CAP;
  }
  __syncthreads();
  int offs[8];
#pragma unroll
  for (int e = 0; e < 8; ++e) offs[e] = lcnt[tid][e];
  for (int j = 0; j < 64; ++j) {
    int ent = base + j; int t = ent >> 1; int k = ent & 1;
    int2 ee = e01[t];
    int ex = k ? ee.y : ee.x;
    float pr = k ? p01[t].y : p01[t].x;
    int pos = offs[ex]++;
    if (pos < CAP) {
      int row = NTOK + ex * CAP + pos;
      tok_row[row] = t;
      scale_row[row] = pr;
    }
  }
  if (tid == 0) {
    float s = 0.f;
    for (int e = 0; e < 8; ++e) s += ((float)afc[e] / 8192.f) * (aps[e] / 8192.f);
    *aux_out = 0.08f * s;  // AUX_COEF * E = 0.01 * 8
  }
}

// ---------------- grouped GEMM, 128x128 tile, BK=64, 4 waves, single-buffer (m97 structure) ----------------
// R8/R10-verified. Per K-step: 8 global_load_lds/wave -> __syncthreads
// (compiler emits vmcnt(0)) -> 16 ds_read_b128 + 32 MFMA -> __syncthreads.
// Latency hiding via 4 resident blocks/CU (33KB LDS, launch_bounds(256,4):
// VGPR cap 512/4 = 128 >= ~124 used -- do NOT raise waves/EU, acc spills: R9).
// XOR chunk-swizzle: LDS[row][c] = global[row][c^(row&7)] (16B chunks),
// staged via swizzled per-lane SOURCE, read with matching XOR (0 conflicts).
// EPI==1: H = bf16(relu(acc)^2)   EPI==2: atomicAdd(y[tok][col], acc*scale)
template <int KD, int NDT, bool GATHER, int EPI>
__global__ __launch_bounds__(256, 4) void gemm_kernel(
    const __bf16* __restrict__ A, const __bf16* __restrict__ B,
    __bf16* __restrict__ Hout, float* __restrict__ Yout,
    const int* __restrict__ counts, const int* __restrict__ tok_row,
    const float* __restrict__ scale_row) {
  constexpr int NCT = NDT / 128;
  constexpr int SH = NTOK / 128;   // 64 shared row-tiles
  constexpr int ET = CAP / 128;    // 20 expert row-tiles (worst case)
  // XCD bijective remap + 4-rt chunks (nwg%8==0, nwg%(4*NCT)==0 hold)
  int nwg = gridDim.x;
  int lin = (blockIdx.x & 7) * (nwg >> 3) + (blockIdx.x >> 3);
  int rem = lin % (4 * NCT);
  int rt = (lin / (4 * NCT)) * 4 + (rem & 3);
  int ct = rem >> 2;

  int g, i0, rowbase;
  if (rt < SH) { g = 8; rowbase = 0; i0 = rt << 7; }
  else { int r = rt - SH; g = r / ET; i0 = (r % ET) << 7; rowbase = NTOK + g * CAP; }
  int cnt = (g == 8) ? NTOK : counts[g];
  if (i0 >= cnt) return;  // uniform early-exit

  __shared__ __align__(16) __bf16 As[128 * 64];   // 16 KB
  __shared__ __align__(16) __bf16 Bs[128 * 64];   // 16 KB
  __shared__ int   toksL[128];
  __shared__ float sclL[128];

  int tid = threadIdx.x, lane = tid & 63, wid = tid >> 6;

  if (tid < 128) {
    int i = i0 + tid; if (i > cnt - 1) i = cnt - 1;  // pad rows duplicate last valid
    toksL[tid] = tok_row[rowbase + i];
    if (EPI == 2) sclL[tid] = scale_row[rowbase + i];
  }
  __syncthreads();

  // staging pointers: 8 lanes cover one 128B k-row; 16B chunk swizzled by row&7
  int rsub = lane >> 3, csub = lane & 7;
  int csw = (csub ^ rsub) * 16;
  const char* aP[4];
  const char* bP[4];
  const char* Bg = (const char*)B + (size_t)g * NDT * KD * 2;
#pragma unroll
  for (int t = 0; t < 4; ++t) {
    int ia = wid * 32 + t * 8 + rsub;
    size_t arow = GATHER ? (size_t)toksL[ia] : (size_t)(rowbase + i0 + ia);
    aP[t] = (const char*)A + arow * (size_t)(KD * 2) + csw;
    int ib = ct * 128 + wid * 32 + t * 8 + rsub;
    bP[t] = Bg + (size_t)ib * (KD * 2) + csw;
  }

  f32x4 acc[4][4];
#pragma unroll
  for (int m2 = 0; m2 < 4; ++m2)
#pragma unroll
    for (int n2 = 0; n2 < 4; ++n2) acc[m2][n2] = f32x4{0.f, 0.f, 0.f, 0.f};

  int wr = wid >> 1, wc = wid & 1;   // wave tile 64x64 at (wr*64, wc*64)
  // hoisted LDS read offsets (element units); chunk' = chunk ^ (row&7), row&7 == lane&7
  int rA[4], rB[4], cS[2];
#pragma unroll
  for (int m2 = 0; m2 < 4; ++m2) rA[m2] = (wr * 64 + m2 * 16 + (lane & 15)) * 64;
#pragma unroll
  for (int n2 = 0; n2 < 4; ++n2) rB[n2] = (wc * 64 + n2 * 16 + (lane & 15)) * 64;
#pragma unroll
  for (int kk = 0; kk < 2; ++kk) cS[kk] = ((kk * 4 + (lane >> 4)) ^ (lane & 7)) * 8;

  // m97 structure: stage -> sync -> compute -> sync, single buffer.
  for (int k0 = 0; k0 < KD; k0 += 64) {
    size_t kb = (size_t)k0 * 2;
#pragma unroll
    for (int t = 0; t < 4; ++t) {
      load_lds16(aP[t] + kb, &As[(wid * 32 + t * 8) * 64]);
      load_lds16(bP[t] + kb, &Bs[(wid * 32 + t * 8) * 64]);
    }
    __syncthreads();   // compiler inserts s_waitcnt vmcnt(0) before barrier
#pragma unroll
    for (int kk = 0; kk < 2; ++kk) {
      bf16x8 af[4], bfr[4];
#pragma unroll
      for (int m2 = 0; m2 < 4; ++m2) af[m2] = *(const bf16x8*)&As[rA[m2] + cS[kk]];
#pragma unroll
      for (int n2 = 0; n2 < 4; ++n2) bfr[n2] = *(const bf16x8*)&Bs[rB[n2] + cS[kk]];
#pragma unroll
      for (int m2 = 0; m2 < 4; ++m2)
#pragma unroll
        for (int n2 = 0; n2 < 4; ++n2)
          acc[m2][n2] = __builtin_amdgcn_mfma_f32_16x16x32_bf16(af[m2], bfr[n2], acc[m2][n2], 0, 0, 0);
    }
    __syncthreads();   // protect LDS reuse next iteration
  }

  // epilogue; C/D frag: col = lane&15, row = (lane>>4)*4 + reg  [verified m89/m91]
#pragma unroll
  for (int m2 = 0; m2 < 4; ++m2) {
    int rb = wr * 64 + m2 * 16 + ((lane >> 4) << 2);
#pragma unroll
    for (int n2 = 0; n2 < 4; ++n2) {
      int col = ct * 128 + wc * 64 + n2 * 16 + (lane & 15);
#pragma unroll
      for (int r = 0; r < 4; ++r) {
        int grow = i0 + rb + r;
        if (grow < cnt) {
          float v = acc[m2][n2][r];
          if constexpr (EPI == 1) {
            v = fmaxf(v, 0.f);
            Hout[(size_t)(rowbase + grow) * NDT + col] = (__bf16)(v * v);
          } else {
            atomicAdd(&Yout[(size_t)toksL[rb + r] * NDT + col], v * sclL[rb + r]);
          }
        }
      }
    }
  }
}

extern "C" void kernel_launch(void* const* d_in, const int* in_sizes, int n_in,
                              void* d_out, int out_size, void* d_ws, size_t ws_size,
                              hipStream_t stream) {
  const float* x      = (const float*)d_in[0];
  const float* rw     = (const float*)d_in[1];
  const float* wfc    = (const float*)d_in[2];
  const float* wproj  = (const float*)d_in[3];
  const float* wsfc   = (const float*)d_in[4];
  const float* wsproj = (const float*)d_in[5];
  float* y = (float*)d_out;

  char* ws = (char*)d_ws;
  size_t off = 0;
  auto alloc = [&](size_t bytes) {
    void* p = ws + off;
    off += (bytes + 1023) & ~(size_t)1023;
    return p;
  };
  __bf16* xbf      = (__bf16*)alloc((size_t)NTOK * DDIM * 2);          // 16 MB
  __bf16* B1       = (__bf16*)alloc((size_t)9 * HDIM * DDIM * 2);      // 26 MB [9][1408][1024]
  __bf16* B2       = (__bf16*)alloc((size_t)9 * DDIM * HDIM * 2);      // 26 MB [9][1024][1408]
  __bf16* H        = (__bf16*)alloc((size_t)NROWS * HDIM * 2);         // 81 MB
  int*    tok_row  = (int*)alloc((size_t)NROWS * 4);
  float*  scale_row= (float*)alloc((size_t)NROWS * 4);
  int2*   e01      = (int2*)alloc((size_t)NTOK * 8);
  float2* p01      = (float2*)alloc((size_t)NTOK * 8);
  int*    counts   = (int*)alloc(1024);
  float*  psum_part= (float*)alloc(256 * 8 * 4);
  int*    fcnt_part= (int*)alloc(256 * 8 * 4);
  (void)ws_size; (void)out_size; (void)in_sizes; (void)n_in;

  // prep: router+convx (256) | zero y (2048) | tconv wfc/wsfc/wproj/wsproj
  prep_kernel<<<27648, 256, 0, stream>>>(x, rw, xbf, e01, p01, tok_row, scale_row,
                                         psum_part, fcnt_part,
                                         wfc, wsfc, wproj, wsproj, B1, B2, y);
  dispatch_kernel<<<1, 256, 0, stream>>>(e01, p01, tok_row, scale_row, counts,
                                         psum_part, fcnt_part, y + YN);
  // GEMM1: H = relu(gather(x) @ B1)^2 ; 128x128 tiles: (64 + 8*20) rt * 11 ct = 2464
  gemm_kernel<1024, 1408, true, 1><<<2464, 256, 0, stream>>>(
      xbf, B1, H, nullptr, counts, tok_row, scale_row);
  // GEMM2: y[tok] += scale * (H @ B2) ; 128x128 tiles: 224 rt * 8 ct = 1792
  gemm_kernel<1408, 1024, false, 2><<<1792, 256, 0, stream>>>(
      H, B2, nullptr, y, counts, tok_row, scale_row);
}

// Round 13
// 333.323 us; speedup vs baseline: 1.0018x; 1.0018x over previous
//
#include <hip/hip_runtime.h>

// MoE forward, MI355X. fp32 router/dispatch (exact top-k), bf16 MFMA grouped
// GEMMs (9 groups = 8 experts + shared), fp32-atomic scatter-combine.
// R12: fix R11's prep regression. Fused prep kept (router+convx | zero y |
// 4x tconv in one kernel) but shared memory shrunk 33KB -> 4.2KB: router
// branch reads rw from GLOBAL (32KB, L1/L2-resident) instead of LDS-caching.
// R11 lesson: fused-kernel static LDS = max over branches; the 32KB router
// cache capped ALL 27648 blocks at 4 blocks/CU. GEMMs byte-identical to
// R10/R11 (128x128, 4 waves, single-buffer, 4 blocks/CU; 131us each x5 runs).

#define NTOK 8192
#define DDIM 1024
#define HDIM 1408
#define CAP  2560
#define NROWS (NTOK + 8*CAP)   // 28672 GEMM rows: [0,8192) shared, then 8*2560 expert slots
#define YN   8388608           // NTOK*DDIM

typedef __bf16 bf16x8 __attribute__((ext_vector_type(8)));
typedef float  f32x4  __attribute__((ext_vector_type(4)));

typedef __attribute__((address_space(1))) void gvoid_t;
typedef __attribute__((address_space(3))) void svoid_t;

static __device__ __forceinline__ void load_lds16(const void* g, void* l) {
  // 16B per lane, LDS dest = wave-uniform base + lane*16 (linear)
  __builtin_amdgcn_global_load_lds((gvoid_t*)g, (svoid_t*)l, 16, 0, 0);
}

// ---------------- fused prep: router+convx | zero y | 4x weight transpose ----------------
// Block ranges: [0,256) router, [256,2304) zero y, [2304,13568) wfc,
// [13568,14976) wsfc, [14976,26240) wproj, [26240,27648) wsproj.
// Shared = 4.2KB (tconv tile) so tconv/zero blocks keep high occupancy.
__device__ __forceinline__ void tconv_body(const float* __restrict__ in,
                                           __bf16* __restrict__ out,
                                           int R, int C, int bx, int by,
                                           float* shbuf, int tid) {
  float (*t)[33] = (float(*)[33])shbuf;
  int c0 = bx * 32, r0 = by * 32;
  int tx = tid & 31, ty = tid >> 5;  // (32,8)
#pragma unroll
  for (int k2 = 0; k2 < 4; ++k2)
    t[ty + k2 * 8][tx] = in[(size_t)(r0 + ty + k2 * 8) * C + c0 + tx];
  __syncthreads();
#pragma unroll
  for (int k2 = 0; k2 < 4; ++k2)
    out[(size_t)(c0 + ty + k2 * 8) * R + r0 + tx] = (__bf16)t[tx][ty + k2 * 8];
}

__global__ __launch_bounds__(256) void prep_kernel(
    const float* __restrict__ x, const float* __restrict__ rw,
    __bf16* __restrict__ xbf,
    int2* __restrict__ e01, float2* __restrict__ p01,
    int* __restrict__ tok_row, float* __restrict__ scale_row,
    float* __restrict__ psum_part, int* __restrict__ fcnt_part,
    const float* __restrict__ wfc, const float* __restrict__ wsfc,
    const float* __restrict__ wproj, const float* __restrict__ wsproj,
    __bf16* __restrict__ B1, __bf16* __restrict__ B2,
    float* __restrict__ y) {
  __shared__ float shbuf[1056];   // 32x33 tconv tile (4.2 KB)
  __shared__ float ps[8];
  __shared__ int fc[8];
  int b = blockIdx.x, tid = threadIdx.x;

  if (b < 256) {
    // ---- router + fused x->bf16 convert; rw read from global (L1/L2-resident) ----
    if (tid < 8) { ps[tid] = 0.f; fc[tid] = 0; }
    __syncthreads();
    const float4* rg4 = (const float4*)rw;
    int lane = tid & 63, wid = tid >> 6;
    for (int it = 0; it < 8; ++it) {
      int t = b * 32 + wid * 8 + it;
      const float4* xt = (const float4*)(x + (size_t)t * DDIM);
      float a[8];
#pragma unroll
      for (int e = 0; e < 8; ++e) a[e] = 0.f;
      float4 v[4];
#pragma unroll
      for (int jj = 0; jj < 4; ++jj) {
        v[jj] = xt[lane * 4 + jj];
#pragma unroll
        for (int e = 0; e < 8; ++e) {
          float4 w = rg4[e * 256 + lane * 4 + jj];
          a[e] += v[jj].x * w.x + v[jj].y * w.y + v[jj].z * w.z + v[jj].w * w.w;
        }
      }
      {
        bf16x8 o0, o1;
#pragma unroll
        for (int jj = 0; jj < 2; ++jj) {
          o0[jj * 4 + 0] = (__bf16)v[jj].x; o0[jj * 4 + 1] = (__bf16)v[jj].y;
          o0[jj * 4 + 2] = (__bf16)v[jj].z; o0[jj * 4 + 3] = (__bf16)v[jj].w;
          o1[jj * 4 + 0] = (__bf16)v[jj + 2].x; o1[jj * 4 + 1] = (__bf16)v[jj + 2].y;
          o1[jj * 4 + 2] = (__bf16)v[jj + 2].z; o1[jj * 4 + 3] = (__bf16)v[jj + 2].w;
        }
        __bf16* xo = xbf + (size_t)t * DDIM + lane * 16;
        *(bf16x8*)xo = o0;
        *(bf16x8*)(xo + 8) = o1;
      }
#pragma unroll
      for (int off = 32; off >= 1; off >>= 1)
#pragma unroll
        for (int e = 0; e < 8; ++e) a[e] += __shfl_xor(a[e], off);
      if (lane == 0) {
        int am = 0; float m = a[0];
        for (int e = 1; e < 8; ++e) if (a[e] > m) { m = a[e]; am = e; }
        float s = 0.f, ex[8];
        for (int e = 0; e < 8; ++e) { ex[e] = expf(a[e] - m); s += ex[e]; }
        float inv = 1.f / s;
        int am2 = -1; float m2 = -3.4e38f;
        for (int e = 0; e < 8; ++e) if (e != am && a[e] > m2) { m2 = a[e]; am2 = e; }
        float p0 = ex[am] * inv, p1 = ex[am2] * inv;
        float rn = 1.f / (p0 + p1 + 1e-9f);
        e01[t] = make_int2(am, am2);
        p01[t] = make_float2(p0 * rn, p1 * rn);
        tok_row[t] = t;            // shared-group rows: identity gather, weight 1
        scale_row[t] = 1.f;
        atomicAdd(&fc[am], 1);
        for (int e = 0; e < 8; ++e) atomicAdd(&ps[e], ex[e] * inv);
      }
    }
    __syncthreads();
    if (tid < 8) { psum_part[b * 8 + tid] = ps[tid]; fcnt_part[b * 8 + tid] = fc[tid]; }
    return;
  }
  b -= 256;
  if (b < 2048) {
    // ---- zero y (atomic-combine target) ----
    size_t idx = (size_t)b * 256 + tid;
    float4 z = make_float4(0.f, 0.f, 0.f, 0.f);
    float4* p = (float4*)y;
#pragma unroll
    for (int j = 0; j < 4; ++j) p[idx + (size_t)j * 524288] = z;
    return;
  }
  b -= 2048;
  if (b < 11264) {  // wfc [e][1024][1408] -> B1[e][1408][1024]
    int e = b / 1408, r = b % 1408;
    tconv_body(wfc + (size_t)e * 1024 * 1408, B1 + (size_t)e * HDIM * DDIM,
               1024, 1408, r % 44, r / 44, shbuf, tid);
    return;
  }
  b -= 11264;
  if (b < 1408) {   // wsfc -> B1[8]
    tconv_body(wsfc, B1 + (size_t)8 * HDIM * DDIM, 1024, 1408, b % 44, b / 44, shbuf, tid);
    return;
  }
  b -= 1408;
  if (b < 11264) {  // wproj [e][1408][1024] -> B2[e][1024][1408]
    int e = b / 1408, r = b % 1408;
    tconv_body(wproj + (size_t)e * 1408 * 1024, B2 + (size_t)e * DDIM * HDIM,
               1408, 1024, r % 32, r / 32, shbuf, tid);
    return;
  }
  b -= 11264;
  {                 // wsproj -> B2[8]
    tconv_body(wsproj, B2 + (size_t)8 * DDIM * HDIM, 1408, 1024, b % 32, b / 32, shbuf, tid);
  }
}

// ------- dispatch (+stat reduce +aux): stable rank within expert, capacity drop -------
__global__ __launch_bounds__(256) void dispatch_kernel(
    const int2* __restrict__ e01, const float2* __restrict__ p01,
    int* __restrict__ tok_row, float* __restrict__ scale_row, int* __restrict__ counts,
    const float* __restrict__ psum_part, const int* __restrict__ fcnt_part,
    float* __restrict__ aux_out) {
  __shared__ int lcnt[256][8];
  __shared__ float aps[8];
  __shared__ int afc[8];
  int tid = threadIdx.x;
  // reduce router per-block stats (independent of dispatch logic)
  if (tid < 8) {
    float s = 0.f; int c = 0;
    for (int i = 0; i < 256; ++i) { s += psum_part[i * 8 + tid]; c += fcnt_part[i * 8 + tid]; }
    aps[tid] = s; afc[tid] = c;
  }
  int my[8];
#pragma unroll
  for (int e = 0; e < 8; ++e) my[e] = 0;
  int base = tid * 64;  // 256 threads * 64 entries = 16384 = N*K, contiguous => stable
  for (int j = 0; j < 64; ++j) {
    int ent = base + j; int t = ent >> 1;
    int2 ee = e01[t];
    int ex = (ent & 1) ? ee.y : ee.x;
    my[ex]++;
  }
#pragma unroll
  for (int e = 0; e < 8; ++e) lcnt[tid][e] = my[e];
  __syncthreads();
  if (tid < 8) {
    int run = 0;
    for (int i = 0; i < 256; ++i) { int c = lcnt[i][tid]; lcnt[i][tid] = run; run += c; }
    counts[tid] = run < CAP ? run : CAP;
  }
  __syncthreads();
  int offs[8];
#pragma unroll
  for (int e = 0; e < 8; ++e) offs[e] = lcnt[tid][e];
  for (int j = 0; j < 64; ++j) {
    int ent = base + j; int t = ent >> 1; int k = ent & 1;
    int2 ee = e01[t];
    int ex = k ? ee.y : ee.x;
    float pr = k ? p01[t].y : p01[t].x;
    int pos = offs[ex]++;
    if (pos < CAP) {
      int row = NTOK + ex * CAP + pos;
      tok_row[row] = t;
      scale_row[row] = pr;
    }
  }
  if (tid == 0) {
    float s = 0.f;
    for (int e = 0; e < 8; ++e) s += ((float)afc[e] / 8192.f) * (aps[e] / 8192.f);
    *aux_out = 0.08f * s;  // AUX_COEF * E = 0.01 * 8
  }
}

// ---------------- grouped GEMM, 128x128 tile, BK=64, 4 waves, single-buffer (m97 structure) ----------------
// R8/R10/R11-verified (131us x5 runs). Per K-step: 8 global_load_lds/wave ->
// __syncthreads (compiler emits vmcnt(0)) -> 16 ds_read_b128 + 32 MFMA ->
// __syncthreads. Latency hiding via 4 resident blocks/CU (33KB LDS,
// launch_bounds(256,4): VGPR cap 512/4 = 128 >= ~124 used -- do NOT raise
// waves/EU, acc spills: R9). XOR chunk-swizzle: LDS[row][c] =
// global[row][c^(row&7)] (16B chunks), staged via swizzled per-lane SOURCE,
// read with matching XOR (0 conflicts).
// EPI==1: H = bf16(relu(acc)^2)   EPI==2: atomicAdd(y[tok][col], acc*scale)
template <int KD, int NDT, bool GATHER, int EPI>
__global__ __launch_bounds__(256, 4) void gemm_kernel(
    const __bf16* __restrict__ A, const __bf16* __restrict__ B,
    __bf16* __restrict__ Hout, float* __restrict__ Yout,
    const int* __restrict__ counts, const int* __restrict__ tok_row,
    const float* __restrict__ scale_row) {
  constexpr int NCT = NDT / 128;
  constexpr int SH = NTOK / 128;   // 64 shared row-tiles
  constexpr int ET = CAP / 128;    // 20 expert row-tiles (worst case)
  // XCD bijective remap + 4-rt chunks (nwg%8==0, nwg%(4*NCT)==0 hold)
  int nwg = gridDim.x;
  int lin = (blockIdx.x & 7) * (nwg >> 3) + (blockIdx.x >> 3);
  int rem = lin % (4 * NCT);
  int rt = (lin / (4 * NCT)) * 4 + (rem & 3);
  int ct = rem >> 2;

  int g, i0, rowbase;
  if (rt < SH) { g = 8; rowbase = 0; i0 = rt << 7; }
  else { int r = rt - SH; g = r / ET; i0 = (r % ET) << 7; rowbase = NTOK + g * CAP; }
  int cnt = (g == 8) ? NTOK : counts[g];
  if (i0 >= cnt) return;  // uniform early-exit

  __shared__ __align__(16) __bf16 As[128 * 64];   // 16 KB
  __shared__ __align__(16) __bf16 Bs[128 * 64];   // 16 KB
  __shared__ int   toksL[128];
  __shared__ float sclL[128];

  int tid = threadIdx.x, lane = tid & 63, wid = tid >> 6;

  if (tid < 128) {
    int i = i0 + tid; if (i > cnt - 1) i = cnt - 1;  // pad rows duplicate last valid
    toksL[tid] = tok_row[rowbase + i];
    if (EPI == 2) sclL[tid] = scale_row[rowbase + i];
  }
  __syncthreads();

  // staging pointers: 8 lanes cover one 128B k-row; 16B chunk swizzled by row&7
  int rsub = lane >> 3, csub = lane & 7;
  int csw = (csub ^ rsub) * 16;
  const char* aP[4];
  const char* bP[4];
  const char* Bg = (const char*)B + (size_t)g * NDT * KD * 2;
#pragma unroll
  for (int t = 0; t < 4; ++t) {
    int ia = wid * 32 + t * 8 + rsub;
    size_t arow = GATHER ? (size_t)toksL[ia] : (size_t)(rowbase + i0 + ia);
    aP[t] = (const char*)A + arow * (size_t)(KD * 2) + csw;
    int ib = ct * 128 + wid * 32 + t * 8 + rsub;
    bP[t] = Bg + (size_t)ib * (KD * 2) + csw;
  }

  f32x4 acc[4][4];
#pragma unroll
  for (int m2 = 0; m2 < 4; ++m2)
#pragma unroll
    for (int n2 = 0; n2 < 4; ++n2) acc[m2][n2] = f32x4{0.f, 0.f, 0.f, 0.f};

  int wr = wid >> 1, wc = wid & 1;   // wave tile 64x64 at (wr*64, wc*64)
  // hoisted LDS read offsets (element units); chunk' = chunk ^ (row&7), row&7 == lane&7
  int rA[4], rB[4], cS[2];
#pragma unroll
  for (int m2 = 0; m2 < 4; ++m2) rA[m2] = (wr * 64 + m2 * 16 + (lane & 15)) * 64;
#pragma unroll
  for (int n2 = 0; n2 < 4; ++n2) rB[n2] = (wc * 64 + n2 * 16 + (lane & 15)) * 64;
#pragma unroll
  for (int kk = 0; kk < 2; ++kk) cS[kk] = ((kk * 4 + (lane >> 4)) ^ (lane & 7)) * 8;

  // m97 structure: stage -> sync -> compute -> sync, single buffer.
  for (int k0 = 0; k0 < KD; k0 += 64) {
    size_t kb = (size_t)k0 * 2;
#pragma unroll
    for (int t = 0; t < 4; ++t) {
      load_lds16(aP[t] + kb, &As[(wid * 32 + t * 8) * 64]);
      load_lds16(bP[t] + kb, &Bs[(wid * 32 + t * 8) * 64]);
    }
    __syncthreads();   // compiler inserts s_waitcnt vmcnt(0) before barrier
#pragma unroll
    for (int kk = 0; kk < 2; ++kk) {
      bf16x8 af[4], bfr[4];
#pragma unroll
      for (int m2 = 0; m2 < 4; ++m2) af[m2] = *(const bf16x8*)&As[rA[m2] + cS[kk]];
#pragma unroll
      for (int n2 = 0; n2 < 4; ++n2) bfr[n2] = *(const bf16x8*)&Bs[rB[n2] + cS[kk]];
#pragma unroll
      for (int m2 = 0; m2 < 4; ++m2)
#pragma unroll
        for (int n2 = 0; n2 < 4; ++n2)
          acc[m2][n2] = __builtin_amdgcn_mfma_f32_16x16x32_bf16(af[m2], bfr[n2], acc[m2][n2], 0, 0, 0);
    }
    __syncthreads();   // protect LDS reuse next iteration
  }

  // epilogue; C/D frag: col = lane&15, row = (lane>>4)*4 + reg  [verified m89/m91]
#pragma unroll
  for (int m2 = 0; m2 < 4; ++m2) {
    int rb = wr * 64 + m2 * 16 + ((lane >> 4) << 2);
#pragma unroll
    for (int n2 = 0; n2 < 4; ++n2) {
      int col = ct * 128 + wc * 64 + n2 * 16 + (lane & 15);
#pragma unroll
      for (int r = 0; r < 4; ++r) {
        int grow = i0 + rb + r;
        if (grow < cnt) {
          float v = acc[m2][n2][r];
          if constexpr (EPI == 1) {
            v = fmaxf(v, 0.f);
            Hout[(size_t)(rowbase + grow) * NDT + col] = (__bf16)(v * v);
          } else {
            atomicAdd(&Yout[(size_t)toksL[rb + r] * NDT + col], v * sclL[rb + r]);
          }
        }
      }
    }
  }
}

extern "C" void kernel_launch(void* const* d_in, const int* in_sizes, int n_in,
                              void* d_out, int out_size, void* d_ws, size_t ws_size,
                              hipStream_t stream) {
  const float* x      = (const float*)d_in[0];
  const float* rw     = (const float*)d_in[1];
  const float* wfc    = (const float*)d_in[2];
  const float* wproj  = (const float*)d_in[3];
  const float* wsfc   = (const float*)d_in[4];
  const float* wsproj = (const float*)d_in[5];
  float* y = (float*)d_out;

  char* ws = (char*)d_ws;
  size_t off = 0;
  auto alloc = [&](size_t bytes) {
    void* p = ws + off;
    off += (bytes + 1023) & ~(size_t)1023;
    return p;
  };
  __bf16* xbf      = (__bf16*)alloc((size_t)NTOK * DDIM * 2);          // 16 MB
  __bf16* B1       = (__bf16*)alloc((size_t)9 * HDIM * DDIM * 2);      // 26 MB [9][1408][1024]
  __bf16* B2       = (__bf16*)alloc((size_t)9 * DDIM * HDIM * 2);      // 26 MB [9][1024][1408]
  __bf16* H        = (__bf16*)alloc((size_t)NROWS * HDIM * 2);         // 81 MB
  int*    tok_row  = (int*)alloc((size_t)NROWS * 4);
  float*  scale_row= (float*)alloc((size_t)NROWS * 4);
  int2*   e01      = (int2*)alloc((size_t)NTOK * 8);
  float2* p01      = (float2*)alloc((size_t)NTOK * 8);
  int*    counts   = (int*)alloc(1024);
  float*  psum_part= (float*)alloc(256 * 8 * 4);
  int*    fcnt_part= (int*)alloc(256 * 8 * 4);
  (void)ws_size; (void)out_size; (void)in_sizes; (void)n_in;

  // prep: router+convx (256) | zero y (2048) | tconv wfc/wsfc/wproj/wsproj
  prep_kernel<<<27648, 256, 0, stream>>>(x, rw, xbf, e01, p01, tok_row, scale_row,
                                         psum_part, fcnt_part,
                                         wfc, wsfc, wproj, wsproj, B1, B2, y);
  dispatch_kernel<<<1, 256, 0, stream>>>(e01, p01, tok_row, scale_row, counts,
                                         psum_part, fcnt_part, y + YN);
  // GEMM1: H = relu(gather(x) @ B1)^2 ; 128x128 tiles: (64 + 8*20) rt * 11 ct = 2464
  gemm_kernel<1024, 1408, true, 1><<<2464, 256, 0, stream>>>(
      xbf, B1, H, nullptr, counts, tok_row, scale_row);
  // GEMM2: y[tok] += scale * (H @ B2) ; 128x128 tiles: 224 rt * 8 ct = 1792
  gemm_kernel<1408, 1024, false, 2><<<1792, 256, 0, stream>>>(
      H, B2, nullptr, y, counts, tok_row, scale_row);
}

// Round 14
// 320.659 us; speedup vs baseline: 1.0414x; 1.0395x over previous
//
#include <hip/hip_runtime.h>

// MoE forward, MI355X. fp32 router/dispatch (exact top-k), bf16 MFMA grouped
// GEMMs (9 groups = 8 experts + shared), fp32-atomic scatter-combine.
// R13: revert R11/R12 prep fusion (separate kernels beat fused by ~15us,
// confirmed twice). Keep R11's dispatch+aux fusion + router partials. New:
// tconv rebuilt -- 64x32 tile, coalesced reads, bf16x8 (16B) vector stores
// (old version did scalar 2B stores), z=9 grid fuses expert+shared slices:
// 4 tconv launches -> 2. GEMMs byte-identical to R8/R10/R12 (131us x7 runs).

#define NTOK 8192
#define DDIM 1024
#define HDIM 1408
#define CAP  2560
#define NROWS (NTOK + 8*CAP)   // 28672 GEMM rows: [0,8192) shared, then 8*2560 expert slots
#define YN   8388608           // NTOK*DDIM

typedef __bf16 bf16x8 __attribute__((ext_vector_type(8)));
typedef float  f32x4  __attribute__((ext_vector_type(4)));

typedef __attribute__((address_space(1))) void gvoid_t;
typedef __attribute__((address_space(3))) void svoid_t;

static __device__ __forceinline__ void load_lds16(const void* g, void* l) {
  // 16B per lane, LDS dest = wave-uniform base + lane*16 (linear)
  __builtin_amdgcn_global_load_lds((gvoid_t*)g, (svoid_t*)l, 16, 0, 0);
}

// ---------------- zero y ----------------
__global__ __launch_bounds__(256) void zero_kernel(float* __restrict__ y) {
  size_t idx = (size_t)blockIdx.x * 256 + threadIdx.x;
  float4 z = make_float4(0.f, 0.f, 0.f, 0.f);
  float4* p = (float4*)y;
#pragma unroll
  for (int j = 0; j < 4; ++j) p[idx + (size_t)j * 524288] = z;
}

// ------- transpose+convert v2: in[R][C] f32 -> out[C][R] bf16, 64x32 tile, bf16x8 stores -------
// z in [0,8]: z<8 -> expert slice of (in,out); z==8 -> (in_s,out_s) shared.
__global__ __launch_bounds__(256) void tconv2_kernel(
    const float* __restrict__ in, __bf16* __restrict__ out,
    const float* __restrict__ in_s, __bf16* __restrict__ out_s, int R, int C) {
  __shared__ float t[64][33];
  int z = blockIdx.z, tid = threadIdx.x;
  const float* ip = (z < 8) ? in + (size_t)z * R * C : in_s;
  __bf16* op = (z < 8) ? out + (size_t)z * R * C : out_s;
  int c0 = blockIdx.x * 32, r0 = blockIdx.y * 64;
  int tx = tid & 31, ty = tid >> 5;          // read: 8 rows/pass, 128B/row coalesced
#pragma unroll
  for (int k = 0; k < 8; ++k)
    t[ty + k * 8][tx] = ip[(size_t)(r0 + ty + k * 8) * C + c0 + tx];
  __syncthreads();
  int cl = tid >> 3, rq = (tid & 7) * 8;     // write: one bf16x8 (16B) per thread
  bf16x8 o;                                  // LDS bank = (8q+j+p)%32 -> 2-way (free)
#pragma unroll
  for (int j = 0; j < 8; ++j) o[j] = (__bf16)t[rq + j][cl];
  *(bf16x8*)(op + (size_t)(c0 + cl) * R + r0 + rq) = o;
}

// ------- router (+ fused x->bf16 convert): fp32 logits, softmax, top-2, renorm -------
__global__ __launch_bounds__(256) void router_kernel(
    const float* __restrict__ x, const float* __restrict__ rw,
    __bf16* __restrict__ xbf,
    int2* __restrict__ e01, float2* __restrict__ p01,
    int* __restrict__ tok_row, float* __restrict__ scale_row,
    float* __restrict__ psum_part, int* __restrict__ fcnt_part) {
  __shared__ float rwl[8 * 1024];
  __shared__ float ps[8];
  __shared__ int fc[8];
  int tid = threadIdx.x;
  if (tid < 8) { ps[tid] = 0.f; fc[tid] = 0; }
  float4* rl4 = (float4*)rwl;
  const float4* rg4 = (const float4*)rw;
#pragma unroll
  for (int j = 0; j < 8; ++j) rl4[tid + 256 * j] = rg4[tid + 256 * j];
  __syncthreads();
  int lane = tid & 63, wid = tid >> 6;
  for (int it = 0; it < 8; ++it) {
    int t = blockIdx.x * 32 + wid * 8 + it;
    const float4* xt = (const float4*)(x + (size_t)t * DDIM);
    float a[8];
#pragma unroll
    for (int e = 0; e < 8; ++e) a[e] = 0.f;
    float4 v[4];
#pragma unroll
    for (int jj = 0; jj < 4; ++jj) {
      v[jj] = xt[lane * 4 + jj];
#pragma unroll
      for (int e = 0; e < 8; ++e) {
        float4 w = rl4[e * 256 + lane * 4 + jj];
        a[e] += v[jj].x * w.x + v[jj].y * w.y + v[jj].z * w.z + v[jj].w * w.w;
      }
    }
    {
      bf16x8 o0, o1;
#pragma unroll
      for (int jj = 0; jj < 2; ++jj) {
        o0[jj * 4 + 0] = (__bf16)v[jj].x; o0[jj * 4 + 1] = (__bf16)v[jj].y;
        o0[jj * 4 + 2] = (__bf16)v[jj].z; o0[jj * 4 + 3] = (__bf16)v[jj].w;
        o1[jj * 4 + 0] = (__bf16)v[jj + 2].x; o1[jj * 4 + 1] = (__bf16)v[jj + 2].y;
        o1[jj * 4 + 2] = (__bf16)v[jj + 2].z; o1[jj * 4 + 3] = (__bf16)v[jj + 2].w;
      }
      __bf16* xo = xbf + (size_t)t * DDIM + lane * 16;
      *(bf16x8*)xo = o0;
      *(bf16x8*)(xo + 8) = o1;
    }
#pragma unroll
    for (int off = 32; off >= 1; off >>= 1)
#pragma unroll
      for (int e = 0; e < 8; ++e) a[e] += __shfl_xor(a[e], off);
    if (lane == 0) {
      int am = 0; float m = a[0];
      for (int e = 1; e < 8; ++e) if (a[e] > m) { m = a[e]; am = e; }
      float s = 0.f, ex[8];
      for (int e = 0; e < 8; ++e) { ex[e] = expf(a[e] - m); s += ex[e]; }
      float inv = 1.f / s;
      int am2 = -1; float m2 = -3.4e38f;
      for (int e = 0; e < 8; ++e) if (e != am && a[e] > m2) { m2 = a[e]; am2 = e; }
      float p0 = ex[am] * inv, p1 = ex[am2] * inv;
      float rn = 1.f / (p0 + p1 + 1e-9f);
      e01[t] = make_int2(am, am2);
      p01[t] = make_float2(p0 * rn, p1 * rn);
      tok_row[t] = t;            // shared-group rows: identity gather, weight 1
      scale_row[t] = 1.f;
      atomicAdd(&fc[am], 1);
      for (int e = 0; e < 8; ++e) atomicAdd(&ps[e], ex[e] * inv);
    }
  }
  __syncthreads();
  if (tid < 8) { psum_part[blockIdx.x * 8 + tid] = ps[tid]; fcnt_part[blockIdx.x * 8 + tid] = fc[tid]; }
}

// ------- dispatch (+stat reduce +aux): stable rank within expert, capacity drop -------
__global__ __launch_bounds__(256) void dispatch_kernel(
    const int2* __restrict__ e01, const float2* __restrict__ p01,
    int* __restrict__ tok_row, float* __restrict__ scale_row, int* __restrict__ counts,
    const float* __restrict__ psum_part, const int* __restrict__ fcnt_part,
    float* __restrict__ aux_out) {
  __shared__ int lcnt[256][8];
  __shared__ float aps[8];
  __shared__ int afc[8];
  int tid = threadIdx.x;
  if (tid < 8) {
    float s = 0.f; int c = 0;
    for (int i = 0; i < 256; ++i) { s += psum_part[i * 8 + tid]; c += fcnt_part[i * 8 + tid]; }
    aps[tid] = s; afc[tid] = c;
  }
  int my[8];
#pragma unroll
  for (int e = 0; e < 8; ++e) my[e] = 0;
  int base = tid * 64;  // 256 threads * 64 entries = 16384 = N*K, contiguous => stable
  for (int j = 0; j < 64; ++j) {
    int ent = base + j; int t = ent >> 1;
    int2 ee = e01[t];
    int ex = (ent & 1) ? ee.y : ee.x;
    my[ex]++;
  }
#pragma unroll
  for (int e = 0; e < 8; ++e) lcnt[tid][e] = my[e];
  __syncthreads();
  if (tid < 8) {
    int run = 0;
    for (int i = 0; i < 256; ++i) { int c = lcnt[i][tid]; lcnt[i][tid] = run; run += c; }
    counts[tid] = run < CAP ? run : CAP;
  }
  __syncthreads();
  int offs[8];
#pragma unroll
  for (int e = 0; e < 8; ++e) offs[e] = lcnt[tid][e];
  for (int j = 0; j < 64; ++j) {
    int ent = base + j; int t = ent >> 1; int k = ent & 1;
    int2 ee = e01[t];
    int ex = k ? ee.y : ee.x;
    float pr = k ? p01[t].y : p01[t].x;
    int pos = offs[ex]++;
    if (pos < CAP) {
      int row = NTOK + ex * CAP + pos;
      tok_row[row] = t;
      scale_row[row] = pr;
    }
  }
  if (tid == 0) {
    float s = 0.f;
    for (int e = 0; e < 8; ++e) s += ((float)afc[e] / 8192.f) * (aps[e] / 8192.f);
    *aux_out = 0.08f * s;  // AUX_COEF * E = 0.01 * 8
  }
}

// ---------------- grouped GEMM, 128x128 tile, BK=64, 4 waves, single-buffer (m97 structure) ----------------
// R8/R10/R12-verified (131us x7 runs). Per K-step: 8 global_load_lds/wave ->
// __syncthreads (compiler emits vmcnt(0)) -> 16 ds_read_b128 + 32 MFMA ->
// __syncthreads. Latency hiding via 4 resident blocks/CU (33KB LDS,
// launch_bounds(256,4): VGPR cap 512/4 = 128 >= ~124 used -- do NOT raise
// waves/EU, acc spills: R9). XOR chunk-swizzle: LDS[row][c] =
// global[row][c^(row&7)] (16B chunks), staged via swizzled per-lane SOURCE,
// read with matching XOR (0 conflicts).
// EPI==1: H = bf16(relu(acc)^2)   EPI==2: atomicAdd(y[tok][col], acc*scale)
template <int KD, int NDT, bool GATHER, int EPI>
__global__ __launch_bounds__(256, 4) void gemm_kernel(
    const __bf16* __restrict__ A, const __bf16* __restrict__ B,
    __bf16* __restrict__ Hout, float* __restrict__ Yout,
    const int* __restrict__ counts, const int* __restrict__ tok_row,
    const float* __restrict__ scale_row) {
  constexpr int NCT = NDT / 128;
  constexpr int SH = NTOK / 128;   // 64 shared row-tiles
  constexpr int ET = CAP / 128;    // 20 expert row-tiles (worst case)
  // XCD bijective remap + 4-rt chunks (nwg%8==0, nwg%(4*NCT)==0 hold)
  int nwg = gridDim.x;
  int lin = (blockIdx.x & 7) * (nwg >> 3) + (blockIdx.x >> 3);
  int rem = lin % (4 * NCT);
  int rt = (lin / (4 * NCT)) * 4 + (rem & 3);
  int ct = rem >> 2;

  int g, i0, rowbase;
  if (rt < SH) { g = 8; rowbase = 0; i0 = rt << 7; }
  else { int r = rt - SH; g = r / ET; i0 = (r % ET) << 7; rowbase = NTOK + g * CAP; }
  int cnt = (g == 8) ? NTOK : counts[g];
  if (i0 >= cnt) return;  // uniform early-exit

  __shared__ __align__(16) __bf16 As[128 * 64];   // 16 KB
  __shared__ __align__(16) __bf16 Bs[128 * 64];   // 16 KB
  __shared__ int   toksL[128];
  __shared__ float sclL[128];

  int tid = threadIdx.x, lane = tid & 63, wid = tid >> 6;

  if (tid < 128) {
    int i = i0 + tid; if (i > cnt - 1) i = cnt - 1;  // pad rows duplicate last valid
    toksL[tid] = tok_row[rowbase + i];
    if (EPI == 2) sclL[tid] = scale_row[rowbase + i];
  }
  __syncthreads();

  // staging pointers: 8 lanes cover one 128B k-row; 16B chunk swizzled by row&7
  int rsub = lane >> 3, csub = lane & 7;
  int csw = (csub ^ rsub) * 16;
  const char* aP[4];
  const char* bP[4];
  const char* Bg = (const char*)B + (size_t)g * NDT * KD * 2;
#pragma unroll
  for (int t = 0; t < 4; ++t) {
    int ia = wid * 32 + t * 8 + rsub;
    size_t arow = GATHER ? (size_t)toksL[ia] : (size_t)(rowbase + i0 + ia);
    aP[t] = (const char*)A + arow * (size_t)(KD * 2) + csw;
    int ib = ct * 128 + wid * 32 + t * 8 + rsub;
    bP[t] = Bg + (size_t)ib * (KD * 2) + csw;
  }

  f32x4 acc[4][4];
#pragma unroll
  for (int m2 = 0; m2 < 4; ++m2)
#pragma unroll
    for (int n2 = 0; n2 < 4; ++n2) acc[m2][n2] = f32x4{0.f, 0.f, 0.f, 0.f};

  int wr = wid >> 1, wc = wid & 1;   // wave tile 64x64 at (wr*64, wc*64)
  // hoisted LDS read offsets (element units); chunk' = chunk ^ (row&7), row&7 == lane&7
  int rA[4], rB[4], cS[2];
#pragma unroll
  for (int m2 = 0; m2 < 4; ++m2) rA[m2] = (wr * 64 + m2 * 16 + (lane & 15)) * 64;
#pragma unroll
  for (int n2 = 0; n2 < 4; ++n2) rB[n2] = (wc * 64 + n2 * 16 + (lane & 15)) * 64;
#pragma unroll
  for (int kk = 0; kk < 2; ++kk) cS[kk] = ((kk * 4 + (lane >> 4)) ^ (lane & 7)) * 8;

  // m97 structure: stage -> sync -> compute -> sync, single buffer.
  for (int k0 = 0; k0 < KD; k0 += 64) {
    size_t kb = (size_t)k0 * 2;
#pragma unroll
    for (int t = 0; t < 4; ++t) {
      load_lds16(aP[t] + kb, &As[(wid * 32 + t * 8) * 64]);
      load_lds16(bP[t] + kb, &Bs[(wid * 32 + t * 8) * 64]);
    }
    __syncthreads();   // compiler inserts s_waitcnt vmcnt(0) before barrier
#pragma unroll
    for (int kk = 0; kk < 2; ++kk) {
      bf16x8 af[4], bfr[4];
#pragma unroll
      for (int m2 = 0; m2 < 4; ++m2) af[m2] = *(const bf16x8*)&As[rA[m2] + cS[kk]];
#pragma unroll
      for (int n2 = 0; n2 < 4; ++n2) bfr[n2] = *(const bf16x8*)&Bs[rB[n2] + cS[kk]];
#pragma unroll
      for (int m2 = 0; m2 < 4; ++m2)
#pragma unroll
        for (int n2 = 0; n2 < 4; ++n2)
          acc[m2][n2] = __builtin_amdgcn_mfma_f32_16x16x32_bf16(af[m2], bfr[n2], acc[m2][n2], 0, 0, 0);
    }
    __syncthreads();   // protect LDS reuse next iteration
  }

  // epilogue; C/D frag: col = lane&15, row = (lane>>4)*4 + reg  [verified m89/m91]
#pragma unroll
  for (int m2 = 0; m2 < 4; ++m2) {
    int rb = wr * 64 + m2 * 16 + ((lane >> 4) << 2);
#pragma unroll
    for (int n2 = 0; n2 < 4; ++n2) {
      int col = ct * 128 + wc * 64 + n2 * 16 + (lane & 15);
#pragma unroll
      for (int r = 0; r < 4; ++r) {
        int grow = i0 + rb + r;
        if (grow < cnt) {
          float v = acc[m2][n2][r];
          if constexpr (EPI == 1) {
            v = fmaxf(v, 0.f);
            Hout[(size_t)(rowbase + grow) * NDT + col] = (__bf16)(v * v);
          } else {
            atomicAdd(&Yout[(size_t)toksL[rb + r] * NDT + col], v * sclL[rb + r]);
          }
        }
      }
    }
  }
}

extern "C" void kernel_launch(void* const* d_in, const int* in_sizes, int n_in,
                              void* d_out, int out_size, void* d_ws, size_t ws_size,
                              hipStream_t stream) {
  const float* x      = (const float*)d_in[0];
  const float* rw     = (const float*)d_in[1];
  const float* wfc    = (const float*)d_in[2];
  const float* wproj  = (const float*)d_in[3];
  const float* wsfc   = (const float*)d_in[4];
  const float* wsproj = (const float*)d_in[5];
  float* y = (float*)d_out;

  char* ws = (char*)d_ws;
  size_t off = 0;
  auto alloc = [&](size_t bytes) {
    void* p = ws + off;
    off += (bytes + 1023) & ~(size_t)1023;
    return p;
  };
  __bf16* xbf      = (__bf16*)alloc((size_t)NTOK * DDIM * 2);          // 16 MB
  __bf16* B1       = (__bf16*)alloc((size_t)9 * HDIM * DDIM * 2);      // 26 MB [9][1408][1024]
  __bf16* B2       = (__bf16*)alloc((size_t)9 * DDIM * HDIM * 2);      // 26 MB [9][1024][1408]
  __bf16* H        = (__bf16*)alloc((size_t)NROWS * HDIM * 2);         // 81 MB
  int*    tok_row  = (int*)alloc((size_t)NROWS * 4);
  float*  scale_row= (float*)alloc((size_t)NROWS * 4);
  int2*   e01      = (int2*)alloc((size_t)NTOK * 8);
  float2* p01      = (float2*)alloc((size_t)NTOK * 8);
  int*    counts   = (int*)alloc(1024);
  float*  psum_part= (float*)alloc(256 * 8 * 4);
  int*    fcnt_part= (int*)alloc(256 * 8 * 4);
  (void)ws_size; (void)out_size; (void)in_sizes; (void)n_in;

  zero_kernel<<<2048, 256, 0, stream>>>(y);
  // B1: wfc [e][1024][1408] -> [e][1408][1024]; z=8 is wsfc
  tconv2_kernel<<<dim3(44, 16, 9), 256, 0, stream>>>(
      wfc, B1, wsfc, B1 + (size_t)8 * HDIM * DDIM, 1024, 1408);
  // B2: wproj [e][1408][1024] -> [e][1024][1408]; z=8 is wsproj
  tconv2_kernel<<<dim3(32, 22, 9), 256, 0, stream>>>(
      wproj, B2, wsproj, B2 + (size_t)8 * DDIM * HDIM, 1408, 1024);
  router_kernel<<<256, 256, 0, stream>>>(x, rw, xbf, e01, p01, tok_row, scale_row,
                                         psum_part, fcnt_part);
  dispatch_kernel<<<1, 256, 0, stream>>>(e01, p01, tok_row, scale_row, counts,
                                         psum_part, fcnt_part, y + YN);
  // GEMM1: H = relu(gather(x) @ B1)^2 ; 128x128 tiles: (64 + 8*20) rt * 11 ct = 2464
  gemm_kernel<1024, 1408, true, 1><<<2464, 256, 0, stream>>>(
      xbf, B1, H, nullptr, counts, tok_row, scale_row);
  // GEMM2: y[tok] += scale * (H @ B2) ; 128x128 tiles: 224 rt * 8 ct = 1792
  gemm_kernel<1408, 1024, false, 2><<<1792, 256, 0, stream>>>(
      H, B2, nullptr, y, counts, tok_row, scale_row);
}